// Round 18
// baseline (1077.806 us; speedup 1.0000x reference)
//
#include <hip/hip_runtime.h>

#define GRP 8
#define SUBD 64
#define NCODE 1024
#define TLEN 4096
#define NBATCH 8
#define NVEC (NBATCH * TLEN)          // 32768
#define QOUT (NBATCH * 512 * TLEN)    // 16777216
#define ROWS 128                      // rows per block
#define NGRPS (NCODE / 8)             // 128 groups of 8 codes

// ws layout (bytes):
// [0]       double lossAcc[2]
// [64]      float e2[2][8][1024]              64 KB
// [65600]   int idx1[8*32768]                 1 MB
// [1114176] float cbP1[8][128][64][8]         2 MB   panel [g][grp][d][8j]
// [3211328] float cbP2[...]                   2 MB
#define WS_E2   64
#define WS_IDX1 (WS_E2 + 65536)
#define WS_P1   (WS_IDX1 + 1048576)
#define WS_P2   (WS_P1 + 2097152)

typedef const __attribute__((address_space(1))) char GCHAR;
typedef __attribute__((address_space(3))) char LCHAR;
typedef float f2 __attribute__((ext_vector_type(2)));

static __device__ __forceinline__ f2 f2min(f2 a, f2 b) {
    f2 r;
    r[0] = __builtin_fminf(a[0], b[0]);
    r[1] = __builtin_fminf(a[1], b[1]);
    return r;
}

// Fused prologue (verified r17, absmax 0.0): e2 ascending-d fma chain +
// panel repack cbP[g][grp][d][j] = cb[g][grp*8+j][d].
__global__ __launch_bounds__(256) void k_prep(const float* __restrict__ cb1,
                                              const float* __restrict__ cb2,
                                              float* __restrict__ e2,
                                              float* __restrict__ cbP1,
                                              float* __restrict__ cbP2) {
    int i = blockIdx.x * 256 + threadIdx.x;      // 0 .. 16383
    int sel = i >> 13, rest = i & 8191, g = rest >> 10, k = rest & 1023;
    int grp = k >> 3, j = k & 7;
    const float* src = (sel ? cb2 : cb1) + ((size_t)g * NCODE + k) * SUBD;
    float* dst = (sel ? cbP2 : cbP1) + ((size_t)(g * NGRPS + grp) * SUBD) * 8 + j;
    float s = 0.f;
#pragma unroll
    for (int ss = 0; ss < 16; ++ss) {
        float4 v = ((const float4*)src)[ss];
#pragma unroll
        for (int dd = 0; dd < 4; ++dd) {
            float c = ((const float*)&v)[dd];
            s = __builtin_fmaf(c, c, s);           // ascending-d chain
            dst[(4 * ss + dd) * 8] = c;
        }
    }
    e2[i] = s;
}

// r13 GEMM core (763 µs lineage) with value-only pk-min select and
// deferred first-index recovery via per-row chunk rescan.
// Exactness: every distance d_k = fma(-2, acc_k, fl(x2+e2_k)) where acc_k is
// one ascending-d fp32 fma chain (packed slots independent). Hot loop takes
// min (order-independent); earliest chunk with chunkmin == global min found
// by strict-< tracker (ascending ib) + integer-min over (w*16+ib) encodings
// (ascending w = ascending k); rescan recomputes the chunk's 32 distances
// BIT-IDENTICALLY and strict-< scans ascending j == numpy first-index argmin.
template <int STAGE2>
__global__ __launch_bounds__(256, 3) void k_vq(
    const float* __restrict__ x,
    const float* __restrict__ cb1,
    const float* __restrict__ cb2,
    const float* __restrict__ cbP,      // packed panel for search codebook
    const float* __restrict__ e2,       // e2 row for search codebook (8*1024)
    const int* __restrict__ idxPrev,    // idx1 (stage2)
    int* __restrict__ idxOut,           // idx1 (stage1)
    float* __restrict__ outIdxF,
    float* __restrict__ qout,           // stage2
    double* __restrict__ lossAcc)       // stage2
{
    __shared__ __align__(16) float xs[SUBD * ROWS];   // 32 KB [d][row]
    __shared__ float bdH[4 * ROWS];                   // 2 KB  [wave][row] row-min
    __shared__ int   biH[4 * ROWS];                   // 2 KB  [wave][row] cand
    __shared__ float mG[ROWS];                        // 512 B global row min
    __shared__ int   i2s[ROWS];
    __shared__ double wsr[8];

    const int tid = threadIdx.x, w = tid >> 6, lane = tid & 63;
    const int g = blockIdx.y;
    const int row0 = blockIdx.x * ROWS;
    const int bz = row0 / TLEN, t0 = row0 % TLEN;
    const float* xsrc = x + ((size_t)(bz * 512 + g * SUBD)) * TLEN + t0;

    // ---- stage x tile (d-major, linear dest) via global_load_lds ----
    {
#pragma unroll
        for (int q = 0; q < 8; ++q) {
            int inst = w * 8 + q;                 // 0..31, 2 d-rows each
            int d = inst * 2 + (lane >> 5);
            const float* gp = xsrc + (size_t)d * TLEN + (lane & 31) * 4;
            float* lp = xs + inst * 256;          // wave-uniform base
            __builtin_amdgcn_global_load_lds((GCHAR*)gp, (LCHAR*)lp, 16, 0, 0);
        }
    }
    __syncthreads();

    // ---- stage2: residual update + loss1 (row=tid&127, hi=tid>>7) ----
    const int rowB = tid & 127, hi = tid >> 7;
    double ls1 = 0.0;
    int i1 = 0;
    if (STAGE2) {
        i1 = idxPrev[g * NVEC + row0 + rowB];
        const float4* z1v = (const float4*)(cb1 + ((size_t)g * NCODE + i1) * SUBD) + hi * 8;
#pragma unroll
        for (int s = 0; s < 8; ++s) {
            float4 z = z1v[s];
#pragma unroll
            for (int dd = 0; dd < 4; ++dd) {
                int d = hi * 32 + s * 4 + dd;
                float r = xs[d * ROWS + rowB];
                float zz = (&z.x)[dd];
                float tt = zz - r;            // fl(z - r)   (loss1 term)
                float zst = r + tt;           // fl(r + tt)
                ls1 += (double)(tt * tt);
                float r2 = r - zst;           // fl(r - zst) -> residual2
                xs[d * ROWS + rowB] = r2;
            }
        }
        __syncthreads();
    }

    // ---- GEMM + value-min: wave w = codes [w*256,(w+1)*256), lane rows (2l,2l+1) ----
    const int w_u = __builtin_amdgcn_readfirstlane(w);
    const f2* xs2 = (const f2*)xs;                 // [d][64] pairs; pair idx = lane

    f2 x2p = {0.f, 0.f};
#pragma unroll 8
    for (int d = 0; d < SUBD; ++d) {
        f2 rv = xs2[d * 64 + lane];
        x2p = __builtin_elementwise_fma(rv, rv, x2p);    // ascending-d chains
    }
    const f2 x2a2 = {x2p[0], x2p[0]}, x2b2 = {x2p[1], x2p[1]};
    const f2 n2 = {-2.0f, -2.0f};

    const float* e2g = e2 + g * NCODE;
    float m0 = 1e30f, m1 = 1e30f;
    int ib0 = 0, ib1 = 0;

    for (int ib = 0; ib < 8; ++ib) {
        const float* cp = cbP + ((size_t)(g * NGRPS) + w_u * 32 + ib * 4) * (SUBD * 8);
        const float4* cq0 = (const float4*)(cp);
        const float4* cq1 = (const float4*)(cp + 1 * (SUBD * 8));
        const float4* cq2 = (const float4*)(cp + 2 * (SUBD * 8));
        const float4* cq3 = (const float4*)(cp + 3 * (SUBD * 8));
        f2 acc[2][4][4];                          // [row][grp][code-pair]
#pragma unroll
        for (int r = 0; r < 2; ++r)
#pragma unroll
            for (int gg = 0; gg < 4; ++gg)
#pragma unroll
                for (int p = 0; p < 4; ++p) acc[r][gg][p] = (f2){0.f, 0.f};

#pragma unroll 2
        for (int d = 0; d < SUBD; ++d) {
            f2 rv = xs2[d * 64 + lane];
            f2 xa2 = {rv[0], rv[0]}, xb2 = {rv[1], rv[1]};
            const float4* cbs[4] = {cq0, cq1, cq2, cq3};
#pragma unroll
            for (int gg = 0; gg < 4; ++gg) {
                float4 q0 = cbs[gg][2 * d];       // codes 8g+0..3 (imm offset)
                float4 q1 = cbs[gg][2 * d + 1];   // codes 8g+4..7
                f2 cv0 = {q0.x, q0.y}, cv1 = {q0.z, q0.w};
                f2 cv2 = {q1.x, q1.y}, cv3 = {q1.z, q1.w};
                acc[0][gg][0] = __builtin_elementwise_fma(xa2, cv0, acc[0][gg][0]);
                acc[0][gg][1] = __builtin_elementwise_fma(xa2, cv1, acc[0][gg][1]);
                acc[0][gg][2] = __builtin_elementwise_fma(xa2, cv2, acc[0][gg][2]);
                acc[0][gg][3] = __builtin_elementwise_fma(xa2, cv3, acc[0][gg][3]);
                acc[1][gg][0] = __builtin_elementwise_fma(xb2, cv0, acc[1][gg][0]);
                acc[1][gg][1] = __builtin_elementwise_fma(xb2, cv1, acc[1][gg][1]);
                acc[1][gg][2] = __builtin_elementwise_fma(xb2, cv2, acc[1][gg][2]);
                acc[1][gg][3] = __builtin_elementwise_fma(xb2, cv3, acc[1][gg][3]);
            }
        }

        // value-only select: 3 packed ops per code-pair per row
        f2 cmA = {1e30f, 1e30f}, cmB = {1e30f, 1e30f};
#pragma unroll
        for (int gg = 0; gg < 4; ++gg) {
            const float4* e4 = (const float4*)(e2g + w_u * 256 + ib * 32 + gg * 8);
            float4 e0 = e4[0], e1 = e4[1];
            f2 ep[4] = {{e0.x, e0.y}, {e0.z, e0.w}, {e1.x, e1.y}, {e1.z, e1.w}};
#pragma unroll
            for (int p = 0; p < 4; ++p) {
                f2 tva = x2a2 + ep[p];                                   // fl(x2+e2)
                f2 da = __builtin_elementwise_fma(n2, acc[0][gg][p], tva);
                cmA = f2min(cmA, da);
                f2 tvb = x2b2 + ep[p];
                f2 db = __builtin_elementwise_fma(n2, acc[1][gg][p], tvb);
                cmB = f2min(cmB, db);
            }
        }
        float cA = __builtin_fminf(cmA[0], cmA[1]);
        float cB = __builtin_fminf(cmB[0], cmB[1]);
        if (cA < m0) { m0 = cA; ib0 = ib; }       // strict <: first chunk kept
        if (cB < m1) { m1 = cB; ib1 = ib; }
    }
    bdH[w * ROWS + 2 * lane]     = m0;
    bdH[w * ROWS + 2 * lane + 1] = m1;
    __syncthreads();

    // ---- per-row global min (value only) ----
    if (tid < ROWS) {
        float m = bdH[tid];
#pragma unroll
        for (int wv = 1; wv < 4; ++wv) m = __builtin_fminf(m, bdH[wv * ROWS + tid]);
        mG[tid] = m;
    }
    __syncthreads();

    // ---- candidate (w,chunk) encodings; min-merge = earliest ascending k ----
    {
        float g0 = mG[2 * lane], g1 = mG[2 * lane + 1];
        biH[w * ROWS + 2 * lane]     = (m0 == g0) ? (w_u * 16 + ib0) : 4096;
        biH[w * ROWS + 2 * lane + 1] = (m1 == g1) ? (w_u * 16 + ib1) : 4096;
    }
    __syncthreads();

    // ---- per-row: earliest chunk, bit-exact rescan for first index ----
    if (tid < ROWS) {
        int c = biH[tid];
#pragma unroll
        for (int wv = 1; wv < 4; ++wv) {
            int o = biH[wv * ROWS + tid];
            if (o < c) c = o;
        }
        int wstar = c >> 4, ibstar = c & 15;

        float xr[64];
#pragma unroll
        for (int d = 0; d < SUBD; ++d) xr[d] = xs[d * ROWS + tid];
        float x2r = 0.f;
#pragma unroll
        for (int d = 0; d < SUBD; ++d) x2r = __builtin_fmaf(xr[d], xr[d], x2r);

        int kbase = wstar * 256 + ibstar * 32;
        const float* cpR = cbP + ((size_t)(g * NGRPS) + wstar * 32 + ibstar * 4) * (SUBD * 8);
        float best = 1e30f;
        int bj = 0;
#pragma unroll
        for (int gg = 0; gg < 4; ++gg) {
            const float4* c4 = (const float4*)(cpR + gg * (SUBD * 8));
            float a8[8];
#pragma unroll
            for (int j = 0; j < 8; ++j) a8[j] = 0.f;
#pragma unroll 4
            for (int d = 0; d < SUBD; ++d) {
                float4 q0 = c4[2 * d];
                float4 q1 = c4[2 * d + 1];
                float xv = xr[d];
                a8[0] = __builtin_fmaf(xv, q0.x, a8[0]);   // ascending-d chains
                a8[1] = __builtin_fmaf(xv, q0.y, a8[1]);
                a8[2] = __builtin_fmaf(xv, q0.z, a8[2]);
                a8[3] = __builtin_fmaf(xv, q0.w, a8[3]);
                a8[4] = __builtin_fmaf(xv, q1.x, a8[4]);
                a8[5] = __builtin_fmaf(xv, q1.y, a8[5]);
                a8[6] = __builtin_fmaf(xv, q1.z, a8[6]);
                a8[7] = __builtin_fmaf(xv, q1.w, a8[7]);
            }
#pragma unroll
            for (int j = 0; j < 8; ++j) {
                int kk = kbase + gg * 8 + j;                         // ascending k
                float tv = x2r + e2g[kk];                            // fl(x2 + e2)
                float dist = __builtin_fmaf(-2.0f, a8[j], tv);       // bit-identical
                if (dist < best) { best = dist; bj = gg * 8 + j; }   // strict <
            }
        }
        int bi = kbase + bj;
        int nv = row0 + tid;
        outIdxF[(size_t)g * NVEC + nv] = (float)bi;
        if (!STAGE2) idxOut[g * NVEC + nv] = bi;
        else i2s[tid] = bi;
    }

    // ---- stage2 fused epilogue: output + loss2 (verbatim r13 exprs) ----
    double ls2 = 0.0;
    if (STAGE2) {
        __syncthreads();
        int bi = i2s[rowB];
        const float4* z1v = (const float4*)(cb1 + ((size_t)g * NCODE + i1) * SUBD) + hi * 8;
        const float4* z2v = (const float4*)(cb2 + ((size_t)g * NCODE + bi) * SUBD) + hi * 8;
        const float* xp = xsrc + rowB;
        float* op = qout + ((size_t)(bz * 512 + g * SUBD)) * TLEN + t0 + rowB;
#pragma unroll
        for (int s = 0; s < 8; ++s) {
            float4 z1 = z1v[s];
            float4 z2 = z2v[s];
#pragma unroll
            for (int dd = 0; dd < 4; ++dd) {
                int d = hi * 32 + s * 4 + dd;
                float xv = xp[(size_t)d * TLEN];
                float r2 = xs[d * ROWS + rowB];     // residual2 (bit-exact)
                float z1f = (&z1.x)[dd];
                float z2f = (&z2.x)[dd];
                float t1 = z1f - xv;
                float zst1 = xv + t1;
                float t2 = z2f - r2;                // fl(z2 - r2) (loss2)
                float zst2 = r2 + t2;
                float qv = zst1 + zst2;             // fl(zst1 + zst2)
                op[(size_t)d * TLEN] = qv;
                ls2 += (double)(t2 * t2);
            }
        }

        // block reduce both losses, 2 atomics per block
#pragma unroll
        for (int off = 32; off; off >>= 1) {
            ls1 += __shfl_down(ls1, off, 64);
            ls2 += __shfl_down(ls2, off, 64);
        }
        if (lane == 0) { wsr[w] = ls1; wsr[4 + w] = ls2; }
        __syncthreads();
        if (tid == 0)
            atomicAdd(lossAcc + 0, wsr[0] + wsr[1] + wsr[2] + wsr[3]);
        else if (tid == 64)
            atomicAdd(lossAcc + 1, wsr[4] + wsr[5] + wsr[6] + wsr[7]);
    }
}

__global__ void k_final(float* __restrict__ lossOut, const double* __restrict__ lossAcc) {
    // loss_i = 1.25 * mean_i ; total = (l1+l2)/2 = 0.625*(m1+m2)
    double m = (lossAcc[0] + lossAcc[1]) / (double)QOUT;
    lossOut[0] = (float)(0.625 * m);
}

extern "C" void kernel_launch(void* const* d_in, const int* in_sizes, int n_in,
                              void* d_out, int out_size, void* d_ws, size_t ws_size,
                              hipStream_t stream) {
    const float* x   = (const float*)d_in[0];
    const float* cb1 = (const float*)d_in[1];
    const float* cb2 = (const float*)d_in[2];
    float* out = (float*)d_out;

    char* ws = (char*)d_ws;
    double* lossAcc = (double*)ws;
    float* e2   = (float*)(ws + WS_E2);
    int*   idx1 = (int*)(ws + WS_IDX1);
    float* cbP1 = (float*)(ws + WS_P1);
    float* cbP2 = (float*)(ws + WS_P2);

    hipMemsetAsync(ws, 0, 16, stream);

    k_prep<<<dim3(64), dim3(256), 0, stream>>>(cb1, cb2, e2, cbP1, cbP2);

    dim3 grid(NVEC / ROWS, GRP);                           // (256, 8)
    float* outIdx = out + QOUT + 1;
    k_vq<0><<<grid, dim3(256), 0, stream>>>(x, cb1, cb2, cbP1, e2,
                                            nullptr, idx1, outIdx, nullptr, nullptr);
    k_vq<1><<<grid, dim3(256), 0, stream>>>(x, cb1, cb2, cbP2, e2 + GRP * NCODE,
                                            idx1, nullptr, outIdx + (size_t)GRP * NVEC,
                                            out, lossAcc);
    k_final<<<1, 1, 0, stream>>>(out + QOUT, lossAcc);
}

// Round 19
// 763.365 us; speedup vs baseline: 1.4119x; 1.4119x over previous
//
#include <hip/hip_runtime.h>

#define GRP 8
#define SUBD 64
#define NCODE 1024
#define TLEN 4096
#define NBATCH 8
#define NVEC (NBATCH * TLEN)          // 32768
#define QOUT (NBATCH * 512 * TLEN)    // 16777216
#define ROWS 128                      // rows per block
#define NGRPS (NCODE / 8)             // 128 groups of 8 codes

// ws layout (bytes):
// [0]       double lossAcc[2]
// [64]      float e2[2][8][1024]              64 KB
// [65600]   int idx1[8*32768]                 1 MB
// [1114176] float cbP1[8][128][64][8]         2 MB   panel [g][grp][d][8j]
// [3211328] float cbP2[...]                   2 MB
#define WS_E2   64
#define WS_IDX1 (WS_E2 + 65536)
#define WS_P1   (WS_IDX1 + 1048576)
#define WS_P2   (WS_P1 + 2097152)

typedef const __attribute__((address_space(1))) char GCHAR;
typedef __attribute__((address_space(3))) char LCHAR;
typedef float f2 __attribute__((ext_vector_type(2)));

__global__ __launch_bounds__(256) void k_e2(const float* __restrict__ cb1,
                                            const float* __restrict__ cb2,
                                            float* __restrict__ e2) {
    int i = blockIdx.x * 256 + threadIdx.x;      // 0 .. 16383
    const float* c = (i < GRP * NCODE) ? (cb1 + (size_t)i * SUBD)
                                       : (cb2 + (size_t)(i - GRP * NCODE) * SUBD);
    float s = 0.f;
#pragma unroll
    for (int d = 0; d < SUBD; ++d) s = __builtin_fmaf(c[d], c[d], s);
    e2[i] = s;
}

// Panel repack (verified r4/r9-r18, absmax 0.0): cbP[g][grp][d][j] = cb[g][grp*8+j][d]
__global__ __launch_bounds__(256) void k_panel(const float* __restrict__ cb1,
                                               const float* __restrict__ cb2,
                                               float* __restrict__ cbP1,
                                               float* __restrict__ cbP2) {
    int i = blockIdx.x * 256 + threadIdx.x;      // 0 .. 16383
    int sel = i >> 13, rest = i & 8191, g = rest >> 10, k = rest & 1023;
    int grp = k >> 3, j = k & 7;
    const float* src = (sel ? cb2 : cb1) + ((size_t)g * NCODE + k) * SUBD;
    float* dst = (sel ? cbP2 : cbP1) + ((size_t)(g * NGRPS + grp) * SUBD) * 8 + j;
#pragma unroll
    for (int s = 0; s < 16; ++s) {
        float4 v = ((const float4*)src)[s];
#pragma unroll
        for (int dd = 0; dd < 4; ++dd) dst[(4 * s + dd) * 8] = ((const float*)&v)[dd];
    }
}

// Block: 256 thr = 4 waves over 128 rows. Wave w owns codes [w*256,(w+1)*256),
// 8 chunks of 32 codes (acc = 2 rows x 32 codes packed = 32 f2 = 64 VGPR).
// Lane handles rows (2*lane, 2*lane+1) -> one ds_read_b64 per d.
// Codes loaded as dwordx4 (4 codes/VMEM instr).
// Inner: v_pk_fma_f32 over code pairs; each packed acc element keeps its own
// ascending-d chain (bit-exact). dist = fma(-2,acc,fl(x2+e2)); per-lane k
// ascending, strict <; 4-way merge ascending w == first-index argmin.
template <int STAGE2>
__global__ __launch_bounds__(256, 3) void k_vq(
    const float* __restrict__ x,
    const float* __restrict__ cb1,
    const float* __restrict__ cb2,
    const float* __restrict__ cbP,      // packed panel for search codebook
    const float* __restrict__ e2,       // e2 row for search codebook (8*1024)
    const int* __restrict__ idxPrev,    // idx1 (stage2)
    int* __restrict__ idxOut,           // idx1 (stage1)
    float* __restrict__ outIdxF,
    float* __restrict__ qout,           // stage2
    double* __restrict__ lossAcc)       // stage2
{
    __shared__ __align__(16) float xs[SUBD * ROWS];   // 32 KB [d][row]
    __shared__ float bdH[4 * ROWS];                   // 2 KB
    __shared__ int   biH[4 * ROWS];                   // 2 KB
    __shared__ int   i2s[ROWS];
    __shared__ double wsr[8];

    const int tid = threadIdx.x, w = tid >> 6, lane = tid & 63;
    const int g = blockIdx.y;
    const int row0 = blockIdx.x * ROWS;
    const int bz = row0 / TLEN, t0 = row0 % TLEN;
    const float* xsrc = x + ((size_t)(bz * 512 + g * SUBD)) * TLEN + t0;

    // ---- stage x tile (d-major, linear dest) via global_load_lds ----
    {
#pragma unroll
        for (int q = 0; q < 8; ++q) {
            int inst = w * 8 + q;                 // 0..31, 2 d-rows each
            int d = inst * 2 + (lane >> 5);
            const float* gp = xsrc + (size_t)d * TLEN + (lane & 31) * 4;
            float* lp = xs + inst * 256;          // wave-uniform base
            __builtin_amdgcn_global_load_lds((GCHAR*)gp, (LCHAR*)lp, 16, 0, 0);
        }
    }
    __syncthreads();

    // ---- stage2: residual update + loss1 (256-wide: row=tid&127, hi=tid>>7) ----
    const int rowB = tid & 127, hi = tid >> 7;
    double ls1 = 0.0;
    int i1 = 0;
    if (STAGE2) {
        i1 = idxPrev[g * NVEC + row0 + rowB];
        const float4* z1v = (const float4*)(cb1 + ((size_t)g * NCODE + i1) * SUBD) + hi * 8;
#pragma unroll
        for (int s = 0; s < 8; ++s) {
            float4 z = z1v[s];
#pragma unroll
            for (int dd = 0; dd < 4; ++dd) {
                int d = hi * 32 + s * 4 + dd;
                float r = xs[d * ROWS + rowB];
                float zz = (&z.x)[dd];
                float tt = zz - r;            // fl(z - r)   (loss1 term)
                float zst = r + tt;           // fl(r + tt)
                ls1 += (double)(tt * tt);
                float r2 = r - zst;           // fl(r - zst) -> residual2
                xs[d * ROWS + rowB] = r2;
            }
        }
        __syncthreads();
    }

    // ---- GEMM + argmin: wave w = codes [w*256,(w+1)*256), lane rows (2l, 2l+1) ----
    const int w_u = __builtin_amdgcn_readfirstlane(w);
    const f2* xs2 = (const f2*)xs;                 // [d][64] pairs; pair idx = lane

    f2 x2p = {0.f, 0.f};
#pragma unroll 8
    for (int d = 0; d < SUBD; ++d) {
        f2 rv = xs2[d * 64 + lane];
        x2p = __builtin_elementwise_fma(rv, rv, x2p);    // ascending-d chains
    }
    const float x2a = x2p[0], x2b = x2p[1];

    const float* e2g = e2 + g * NCODE;
    float best[2] = {1e30f, 1e30f};
    int bidx[2] = {0, 0};

    for (int ib = 0; ib < 8; ++ib) {
        const float* cp = cbP + ((size_t)(g * NGRPS) + w_u * 32 + ib * 4) * (SUBD * 8);
        f2 acc[2][4][4];                          // [row][grp][code-pair]
#pragma unroll
        for (int r = 0; r < 2; ++r)
#pragma unroll
            for (int gg = 0; gg < 4; ++gg)
#pragma unroll
                for (int p = 0; p < 4; ++p) acc[r][gg][p] = (f2){0.f, 0.f};

        for (int d = 0; d < SUBD; ++d) {
            f2 rv = xs2[d * 64 + lane];
            f2 xa2 = {rv[0], rv[0]}, xb2 = {rv[1], rv[1]};
#pragma unroll
            for (int gg = 0; gg < 4; ++gg) {
                const float4* c4 = (const float4*)(cp + gg * (SUBD * 8) + d * 8);
                float4 q0 = c4[0];                // codes 8g+0..3
                float4 q1 = c4[1];                // codes 8g+4..7
                f2 cv0 = {q0.x, q0.y}, cv1 = {q0.z, q0.w};
                f2 cv2 = {q1.x, q1.y}, cv3 = {q1.z, q1.w};
                acc[0][gg][0] = __builtin_elementwise_fma(xa2, cv0, acc[0][gg][0]);
                acc[0][gg][1] = __builtin_elementwise_fma(xa2, cv1, acc[0][gg][1]);
                acc[0][gg][2] = __builtin_elementwise_fma(xa2, cv2, acc[0][gg][2]);
                acc[0][gg][3] = __builtin_elementwise_fma(xa2, cv3, acc[0][gg][3]);
                acc[1][gg][0] = __builtin_elementwise_fma(xb2, cv0, acc[1][gg][0]);
                acc[1][gg][1] = __builtin_elementwise_fma(xb2, cv1, acc[1][gg][1]);
                acc[1][gg][2] = __builtin_elementwise_fma(xb2, cv2, acc[1][gg][2]);
                acc[1][gg][3] = __builtin_elementwise_fma(xb2, cv3, acc[1][gg][3]);
            }
        }

#pragma unroll
        for (int gg = 0; gg < 4; ++gg) {
            const float4* e4 = (const float4*)(e2g + w_u * 256 + ib * 32 + gg * 8);
            float4 e0 = e4[0], e1 = e4[1];
#pragma unroll
            for (int p = 0; p < 4; ++p) {
#pragma unroll
                for (int h = 0; h < 2; ++h) {
                    int j = 2 * p + h;
                    int k = w_u * 256 + ib * 32 + gg * 8 + j;            // ascending
                    float ev = (j < 4) ? (&e0.x)[j] : (&e1.x)[j - 4];
                    float tva = x2a + ev;                                // fl(x2 + e2)
                    float da = __builtin_fmaf(-2.0f, acc[0][gg][p][h], tva);
                    if (da < best[0]) { best[0] = da; bidx[0] = k; }
                    float tvb = x2b + ev;
                    float db = __builtin_fmaf(-2.0f, acc[1][gg][p][h], tvb);
                    if (db < best[1]) { best[1] = db; bidx[1] = k; }
                }
            }
        }
    }
    bdH[w * ROWS + 2 * lane]     = best[0];
    biH[w * ROWS + 2 * lane]     = bidx[0];
    bdH[w * ROWS + 2 * lane + 1] = best[1];
    biH[w * ROWS + 2 * lane + 1] = bidx[1];
    __syncthreads();

    // ---- 4-way merge (ascending wave = ascending k; strict <), outputs ----
    if (tid < ROWS) {
        float bd = bdH[tid];
        int   bi = biH[tid];
#pragma unroll
        for (int wv = 1; wv < 4; ++wv) {
            float od = bdH[wv * ROWS + tid];
            int   oi = biH[wv * ROWS + tid];
            if (od < bd) { bd = od; bi = oi; }
        }
        int nv = row0 + tid;
        outIdxF[(size_t)g * NVEC + nv] = (float)bi;
        if (!STAGE2) idxOut[g * NVEC + nv] = bi;
        else i2s[tid] = bi;
    }

    // ---- stage2 fused epilogue: output + loss2 (verbatim exprs) ----
    double ls2 = 0.0;
    if (STAGE2) {
        __syncthreads();
        int bi = i2s[rowB];
        const float4* z1v = (const float4*)(cb1 + ((size_t)g * NCODE + i1) * SUBD) + hi * 8;
        const float4* z2v = (const float4*)(cb2 + ((size_t)g * NCODE + bi) * SUBD) + hi * 8;
        const float* xp = xsrc + rowB;
        float* op = qout + ((size_t)(bz * 512 + g * SUBD)) * TLEN + t0 + rowB;
#pragma unroll
        for (int s = 0; s < 8; ++s) {
            float4 z1 = z1v[s];
            float4 z2 = z2v[s];
#pragma unroll
            for (int dd = 0; dd < 4; ++dd) {
                int d = hi * 32 + s * 4 + dd;
                float xv = xp[(size_t)d * TLEN];
                float r2 = xs[d * ROWS + rowB];     // residual2 (bit-exact)
                float z1f = (&z1.x)[dd];
                float z2f = (&z2.x)[dd];
                float t1 = z1f - xv;
                float zst1 = xv + t1;
                float t2 = z2f - r2;                // fl(z2 - r2) (loss2)
                float zst2 = r2 + t2;
                float qv = zst1 + zst2;             // fl(zst1 + zst2)
                op[(size_t)d * TLEN] = qv;
                ls2 += (double)(t2 * t2);
            }
        }

        // block reduce both losses, 2 atomics per block
#pragma unroll
        for (int off = 32; off; off >>= 1) {
            ls1 += __shfl_down(ls1, off, 64);
            ls2 += __shfl_down(ls2, off, 64);
        }
        if (lane == 0) { wsr[w] = ls1; wsr[4 + w] = ls2; }
        __syncthreads();
        if (tid == 0)
            atomicAdd(lossAcc + 0, wsr[0] + wsr[1] + wsr[2] + wsr[3]);
        else if (tid == 64)
            atomicAdd(lossAcc + 1, wsr[4] + wsr[5] + wsr[6] + wsr[7]);
    }
}

__global__ void k_final(float* __restrict__ lossOut, const double* __restrict__ lossAcc) {
    // loss_i = 1.25 * mean_i ; total = (l1+l2)/2 = 0.625*(m1+m2)
    double m = (lossAcc[0] + lossAcc[1]) / (double)QOUT;
    lossOut[0] = (float)(0.625 * m);
}

extern "C" void kernel_launch(void* const* d_in, const int* in_sizes, int n_in,
                              void* d_out, int out_size, void* d_ws, size_t ws_size,
                              hipStream_t stream) {
    const float* x   = (const float*)d_in[0];
    const float* cb1 = (const float*)d_in[1];
    const float* cb2 = (const float*)d_in[2];
    float* out = (float*)d_out;

    char* ws = (char*)d_ws;
    double* lossAcc = (double*)ws;
    float* e2   = (float*)(ws + WS_E2);
    int*   idx1 = (int*)(ws + WS_IDX1);
    float* cbP1 = (float*)(ws + WS_P1);
    float* cbP2 = (float*)(ws + WS_P2);

    hipMemsetAsync(ws, 0, 16, stream);

    k_e2<<<dim3(64), dim3(256), 0, stream>>>(cb1, cb2, e2);
    k_panel<<<dim3(64), dim3(256), 0, stream>>>(cb1, cb2, cbP1, cbP2);

    dim3 grid(NVEC / ROWS, GRP);                           // (256, 8)
    float* outIdx = out + QOUT + 1;
    k_vq<0><<<grid, dim3(256), 0, stream>>>(x, cb1, cb2, cbP1, e2,
                                            nullptr, idx1, outIdx, nullptr, nullptr);
    k_vq<1><<<grid, dim3(256), 0, stream>>>(x, cb1, cb2, cbP2, e2 + GRP * NCODE,
                                            idx1, nullptr, outIdx + (size_t)GRP * NVEC,
                                            out, lossAcc);
    k_final<<<1, 1, 0, stream>>>(out + QOUT, lossAcc);
}